// Round 1
// baseline (1320.147 us; speedup 1.0000x reference)
//
#include <hip/hip_runtime.h>

#define NPOS 4096
#define CDIM 256
#define FDIM 64

// ---------------------------------------------------------------------------
// Kernel 1: projections  f = x@Wf [8192,64], g = x@Wg [8192,64], h = x@Wh [8192,256]
// One block = 16 rows of x staged in LDS; per-thread register accumulators.
// ---------------------------------------------------------------------------
__global__ __launch_bounds__(256) void proj_kernel(
    const float* __restrict__ x, const float* __restrict__ Wf,
    const float* __restrict__ Wg, const float* __restrict__ Wh,
    float* __restrict__ f, float* __restrict__ g, float* __restrict__ h) {
  __shared__ float xs[16][CDIM];
  const int row0 = blockIdx.x * 16;
  const int t = threadIdx.x;
  {
    const float4* xv = reinterpret_cast<const float4*>(x + (size_t)row0 * CDIM);
    float4* sv = reinterpret_cast<float4*>(&xs[0][0]);
#pragma unroll
    for (int i = 0; i < 4; ++i) sv[t + 256 * i] = xv[t + 256 * i];
  }
  __syncthreads();
  // h projection: thread t owns output column t for all 16 rows
  {
    float acc[16];
#pragma unroll
    for (int r = 0; r < 16; ++r) acc[r] = 0.f;
    for (int k = 0; k < CDIM; k += 4) {
      const float w0 = Wh[(size_t)(k + 0) * CDIM + t];
      const float w1 = Wh[(size_t)(k + 1) * CDIM + t];
      const float w2 = Wh[(size_t)(k + 2) * CDIM + t];
      const float w3 = Wh[(size_t)(k + 3) * CDIM + t];
#pragma unroll
      for (int r = 0; r < 16; ++r) {
        const float4 xv = *reinterpret_cast<const float4*>(&xs[r][k]);
        float a = acc[r];
        a = fmaf(xv.x, w0, a);
        a = fmaf(xv.y, w1, a);
        a = fmaf(xv.z, w2, a);
        a = fmaf(xv.w, w3, a);
        acc[r] = a;
      }
    }
#pragma unroll
    for (int r = 0; r < 16; ++r) h[(size_t)(row0 + r) * CDIM + t] = acc[r];
  }
  // f,g projections: thread t owns column (t&63), rows rb..rb+3
  {
    const int col = t & 63;
    const int rb = (t >> 6) * 4;
    float af[4] = {0.f, 0.f, 0.f, 0.f};
    float ag[4] = {0.f, 0.f, 0.f, 0.f};
    for (int k = 0; k < CDIM; k += 4) {
      const float wf0 = Wf[(size_t)(k + 0) * FDIM + col];
      const float wf1 = Wf[(size_t)(k + 1) * FDIM + col];
      const float wf2 = Wf[(size_t)(k + 2) * FDIM + col];
      const float wf3 = Wf[(size_t)(k + 3) * FDIM + col];
      const float wg0 = Wg[(size_t)(k + 0) * FDIM + col];
      const float wg1 = Wg[(size_t)(k + 1) * FDIM + col];
      const float wg2 = Wg[(size_t)(k + 2) * FDIM + col];
      const float wg3 = Wg[(size_t)(k + 3) * FDIM + col];
#pragma unroll
      for (int r = 0; r < 4; ++r) {
        const float4 xv = *reinterpret_cast<const float4*>(&xs[rb + r][k]);
        float a = af[r], b = ag[r];
        a = fmaf(xv.x, wf0, a); a = fmaf(xv.y, wf1, a);
        a = fmaf(xv.z, wf2, a); a = fmaf(xv.w, wf3, a);
        b = fmaf(xv.x, wg0, b); b = fmaf(xv.y, wg1, b);
        b = fmaf(xv.z, wg2, b); b = fmaf(xv.w, wg3, b);
        af[r] = a; ag[r] = b;
      }
    }
#pragma unroll
    for (int r = 0; r < 4; ++r) {
      f[(size_t)(row0 + rb + r) * FDIM + col] = af[r];
      g[(size_t)(row0 + rb + r) * FDIM + col] = ag[r];
    }
  }
}

// ---------------------------------------------------------------------------
// Kernel 2: s = g @ f^T, streamed in 32x128 chunks.
// Writes RAW s into the beta region of d_out; tracks per-row online (max, sumexp)
// -> mrow/lrow in ws. Thread tile: 2 rows x 8 cols, float4 k-blocking from LDS.
// ---------------------------------------------------------------------------
__global__ __launch_bounds__(256) void qk_kernel(
    const float* __restrict__ f, const float* __restrict__ g,
    float* __restrict__ sraw, float* __restrict__ mrow, float* __restrict__ lrow) {
  __shared__ float gs[32][68];
  __shared__ float fs[128][68];
  const int b = blockIdx.y;
  const int row0 = blockIdx.x * 32;
  const int t = threadIdx.x;
  const int rg = t >> 4;   // 0..15 -> rows rg*2, rg*2+1
  const int cg = t & 15;   // 0..15 -> cols cg*8 .. cg*8+7 (within 128-chunk)

  {
    const float4* gv = reinterpret_cast<const float4*>(g + ((size_t)b * NPOS + row0) * FDIM);
#pragma unroll
    for (int q = 0; q < 2; ++q) {
      const int id = t + 256 * q;   // 512 float4 total
      const float4 v = gv[id];
      const int r = id >> 4, kq = id & 15;
      *reinterpret_cast<float4*>(&gs[r][kq * 4]) = v;
    }
  }

  float m0 = -1e30f, m1 = -1e30f, l0 = 0.f, l1 = 0.f;
  float* srow0 = sraw + (size_t)b * NPOS * NPOS + (size_t)(row0 + rg * 2 + 0) * NPOS;
  float* srow1 = srow0 + NPOS;

  for (int ch = 0; ch < 32; ++ch) {
    __syncthreads();
    {
      const float4* fv = reinterpret_cast<const float4*>(f + ((size_t)b * NPOS + ch * 128) * FDIM);
#pragma unroll
      for (int q = 0; q < 8; ++q) {
        const int id = t + 256 * q;   // 2048 float4 total
        const float4 v = fv[id];
        const int r = id >> 4, kq = id & 15;
        *reinterpret_cast<float4*>(&fs[r][kq * 4]) = v;
      }
    }
    __syncthreads();

    float acc0[8], acc1[8];
#pragma unroll
    for (int j = 0; j < 8; ++j) { acc0[j] = 0.f; acc1[j] = 0.f; }
#pragma unroll
    for (int k = 0; k < FDIM; k += 4) {
      const float4 a0 = *reinterpret_cast<const float4*>(&gs[rg * 2 + 0][k]);
      const float4 a1 = *reinterpret_cast<const float4*>(&gs[rg * 2 + 1][k]);
#pragma unroll
      for (int j = 0; j < 8; ++j) {
        const float4 bq = *reinterpret_cast<const float4*>(&fs[cg * 8 + j][k]);
        float s0 = acc0[j], s1 = acc1[j];
        s0 = fmaf(a0.x, bq.x, s0); s0 = fmaf(a0.y, bq.y, s0);
        s0 = fmaf(a0.z, bq.z, s0); s0 = fmaf(a0.w, bq.w, s0);
        s1 = fmaf(a1.x, bq.x, s1); s1 = fmaf(a1.y, bq.y, s1);
        s1 = fmaf(a1.z, bq.z, s1); s1 = fmaf(a1.w, bq.w, s1);
        acc0[j] = s0; acc1[j] = s1;
      }
    }

    const int cbase = ch * 128 + cg * 8;
    *reinterpret_cast<float4*>(&srow0[cbase]) = make_float4(acc0[0], acc0[1], acc0[2], acc0[3]);
    *reinterpret_cast<float4*>(&srow0[cbase + 4]) = make_float4(acc0[4], acc0[5], acc0[6], acc0[7]);
    *reinterpret_cast<float4*>(&srow1[cbase]) = make_float4(acc1[0], acc1[1], acc1[2], acc1[3]);
    *reinterpret_cast<float4*>(&srow1[cbase + 4]) = make_float4(acc1[4], acc1[5], acc1[6], acc1[7]);

    // online softmax stats
    float cm0 = acc0[0], cm1 = acc1[0];
#pragma unroll
    for (int j = 1; j < 8; ++j) { cm0 = fmaxf(cm0, acc0[j]); cm1 = fmaxf(cm1, acc1[j]); }
    if (cm0 > m0) { l0 *= __expf(m0 - cm0); m0 = cm0; }
    if (cm1 > m1) { l1 *= __expf(m1 - cm1); m1 = cm1; }
    float s0 = 0.f, s1 = 0.f;
#pragma unroll
    for (int j = 0; j < 8; ++j) { s0 += __expf(acc0[j] - m0); s1 += __expf(acc1[j] - m1); }
    l0 += s0; l1 += s1;
  }

  // merge (m,l) across the 16 lanes (cg) sharing each row pair
#pragma unroll
  for (int off = 1; off < 16; off <<= 1) {
    const float om0 = __shfl_xor(m0, off), ol0 = __shfl_xor(l0, off);
    const float om1 = __shfl_xor(m1, off), ol1 = __shfl_xor(l1, off);
    float nm = fmaxf(m0, om0);
    l0 = l0 * __expf(m0 - nm) + ol0 * __expf(om0 - nm); m0 = nm;
    nm = fmaxf(m1, om1);
    l1 = l1 * __expf(m1 - nm) + ol1 * __expf(om1 - nm); m1 = nm;
  }
  if (cg == 0) {
    const int r = b * NPOS + row0 + rg * 2;
    mrow[r] = m0; lrow[r] = l0;
    mrow[r + 1] = m1; lrow[r + 1] = l1;
  }
}

// ---------------------------------------------------------------------------
// Kernel 3: beta = exp(s-m)/l (written back in place in d_out), o = beta @ h,
// out = gamma*o + x. Tile: 16 rows x 256 cols; thread tile 2 rows x 8 cols.
// ---------------------------------------------------------------------------
__global__ __launch_bounds__(256) void pv_kernel(
    const float* __restrict__ h, const float* __restrict__ x,
    const float* __restrict__ mrow, const float* __restrict__ lrow,
    const float* __restrict__ gamma, float* __restrict__ beta,
    float* __restrict__ out) {
  __shared__ float bs[16][68];
  const int b = blockIdx.y;
  const int row0 = blockIdx.x * 16;
  const int t = threadIdx.x;
  const int rg = t >> 5;   // 0..7 -> rows rg*2, rg*2+1
  const int cg = t & 31;   // 0..31 -> cols cg*8 .. cg*8+7

  const float gam = gamma[0];
  float* betab = beta + (size_t)b * NPOS * NPOS;

  // staging assignment (fixed per thread): one float4 of the 16x64 chunk
  const int sr = t >> 4;    // 0..15  (staging row)
  const int skq = t & 15;   // 0..15  (float4 index within row's 64 cols)
  const float mm = mrow[b * NPOS + row0 + sr];
  const float il = __frcp_rn(lrow[b * NPOS + row0 + sr]);

  float acc[2][8];
#pragma unroll
  for (int i = 0; i < 2; ++i)
#pragma unroll
    for (int j = 0; j < 8; ++j) acc[i][j] = 0.f;

  for (int ch = 0; ch < 64; ++ch) {
    __syncthreads();
    {
      const size_t off = (size_t)(row0 + sr) * NPOS + ch * 64 + skq * 4;
      float4 v = *reinterpret_cast<const float4*>(&betab[off]);
      v.x = __expf(v.x - mm) * il;
      v.y = __expf(v.y - mm) * il;
      v.z = __expf(v.z - mm) * il;
      v.w = __expf(v.w - mm) * il;
      *reinterpret_cast<float4*>(&betab[off]) = v;   // final beta output
      *reinterpret_cast<float4*>(&bs[sr][skq * 4]) = v;
    }
    __syncthreads();

    const float* hb = h + ((size_t)b * NPOS + ch * 64) * CDIM + cg * 8;
#pragma unroll 4
    for (int k = 0; k < 64; ++k) {
      const float4 h0 = *reinterpret_cast<const float4*>(&hb[(size_t)k * CDIM]);
      const float4 h1 = *reinterpret_cast<const float4*>(&hb[(size_t)k * CDIM + 4]);
      const float a0 = bs[rg * 2 + 0][k];
      const float a1 = bs[rg * 2 + 1][k];
      acc[0][0] = fmaf(a0, h0.x, acc[0][0]);
      acc[0][1] = fmaf(a0, h0.y, acc[0][1]);
      acc[0][2] = fmaf(a0, h0.z, acc[0][2]);
      acc[0][3] = fmaf(a0, h0.w, acc[0][3]);
      acc[0][4] = fmaf(a0, h1.x, acc[0][4]);
      acc[0][5] = fmaf(a0, h1.y, acc[0][5]);
      acc[0][6] = fmaf(a0, h1.z, acc[0][6]);
      acc[0][7] = fmaf(a0, h1.w, acc[0][7]);
      acc[1][0] = fmaf(a1, h0.x, acc[1][0]);
      acc[1][1] = fmaf(a1, h0.y, acc[1][1]);
      acc[1][2] = fmaf(a1, h0.z, acc[1][2]);
      acc[1][3] = fmaf(a1, h0.w, acc[1][3]);
      acc[1][4] = fmaf(a1, h1.x, acc[1][4]);
      acc[1][5] = fmaf(a1, h1.y, acc[1][5]);
      acc[1][6] = fmaf(a1, h1.z, acc[1][6]);
      acc[1][7] = fmaf(a1, h1.w, acc[1][7]);
    }
  }

  // epilogue: out = gamma*o + x
#pragma unroll
  for (int i = 0; i < 2; ++i) {
    const int row = row0 + rg * 2 + i;
    const size_t o = ((size_t)b * NPOS + row) * CDIM + cg * 8;
    const float4 x0 = *reinterpret_cast<const float4*>(&x[o]);
    const float4 x1 = *reinterpret_cast<const float4*>(&x[o + 4]);
    float4 r0, r1;
    r0.x = fmaf(gam, acc[i][0], x0.x);
    r0.y = fmaf(gam, acc[i][1], x0.y);
    r0.z = fmaf(gam, acc[i][2], x0.z);
    r0.w = fmaf(gam, acc[i][3], x0.w);
    r1.x = fmaf(gam, acc[i][4], x1.x);
    r1.y = fmaf(gam, acc[i][5], x1.y);
    r1.z = fmaf(gam, acc[i][6], x1.z);
    r1.w = fmaf(gam, acc[i][7], x1.w);
    *reinterpret_cast<float4*>(&out[o]) = r0;
    *reinterpret_cast<float4*>(&out[o + 4]) = r1;
  }
}

extern "C" void kernel_launch(void* const* d_in, const int* in_sizes, int n_in,
                              void* d_out, int out_size, void* d_ws, size_t ws_size,
                              hipStream_t stream) {
  (void)in_sizes; (void)n_in; (void)out_size; (void)ws_size;
  const float* x = (const float*)d_in[0];
  const float* Wf = (const float*)d_in[1];
  const float* Wg = (const float*)d_in[2];
  const float* Wh = (const float*)d_in[3];
  const float* gamma = (const float*)d_in[4];

  float* out = (float*)d_out;                                  // [2*4096*256]
  float* beta = out + (size_t)2 * NPOS * CDIM;                 // [2*4096*4096]

  float* f = (float*)d_ws;                                     // [8192*64]
  float* g = f + (size_t)2 * NPOS * FDIM;                      // [8192*64]
  float* h = g + (size_t)2 * NPOS * FDIM;                      // [8192*256]
  float* mrow = h + (size_t)2 * NPOS * CDIM;                   // [8192]
  float* lrow = mrow + 2 * NPOS;                               // [8192]

  hipLaunchKernelGGL(proj_kernel, dim3(2 * NPOS / 16), dim3(256), 0, stream,
                     x, Wf, Wg, Wh, f, g, h);
  hipLaunchKernelGGL(qk_kernel, dim3(NPOS / 32, 2), dim3(256), 0, stream,
                     f, g, beta, mrow, lrow);
  hipLaunchKernelGGL(pv_kernel, dim3(NPOS / 16, 2), dim3(256), 0, stream,
                     h, x, mrow, lrow, gamma, beta, out);
}

// Round 2
// 271.178 us; speedup vs baseline: 4.8682x; 4.8682x over previous
//
#include <hip/hip_runtime.h>

#define NPOS 4096
#define CDIM 256
#define FDIM 64

typedef short short8 __attribute__((ext_vector_type(8)));
typedef float f32x4 __attribute__((ext_vector_type(4)));

__device__ __forceinline__ unsigned short f2bf(float v) {
  unsigned u = __float_as_uint(v);
  unsigned r = (u + 0x7fffu + ((u >> 16) & 1u)) >> 16;  // RNE
  return (unsigned short)r;
}

// ---------------------------------------------------------------------------
// Kernel 1: projections  f = x@Wf [8192,64], g = x@Wg [8192,64],
// h_t = (x@Wh)^T in bf16: h_t[b][col 256][row 4096]
// ---------------------------------------------------------------------------
__global__ __launch_bounds__(256) void proj_kernel(
    const float* __restrict__ x, const float* __restrict__ Wf,
    const float* __restrict__ Wg, const float* __restrict__ Wh,
    float* __restrict__ f, float* __restrict__ g, unsigned short* __restrict__ h_t) {
  __shared__ float xs[16][CDIM];
  const int row0 = blockIdx.x * 16;
  const int t = threadIdx.x;
  {
    const float4* xv = reinterpret_cast<const float4*>(x + (size_t)row0 * CDIM);
    float4* sv = reinterpret_cast<float4*>(&xs[0][0]);
#pragma unroll
    for (int i = 0; i < 4; ++i) sv[t + 256 * i] = xv[t + 256 * i];
  }
  __syncthreads();
  // h projection: thread t owns output column t for all 16 rows -> h_t bf16
  {
    float acc[16];
#pragma unroll
    for (int r = 0; r < 16; ++r) acc[r] = 0.f;
    for (int k = 0; k < CDIM; k += 4) {
      const float w0 = Wh[(size_t)(k + 0) * CDIM + t];
      const float w1 = Wh[(size_t)(k + 1) * CDIM + t];
      const float w2 = Wh[(size_t)(k + 2) * CDIM + t];
      const float w3 = Wh[(size_t)(k + 3) * CDIM + t];
#pragma unroll
      for (int r = 0; r < 16; ++r) {
        const float4 xv = *reinterpret_cast<const float4*>(&xs[r][k]);
        float a = acc[r];
        a = fmaf(xv.x, w0, a);
        a = fmaf(xv.y, w1, a);
        a = fmaf(xv.z, w2, a);
        a = fmaf(xv.w, w3, a);
        acc[r] = a;
      }
    }
    const int b = row0 >> 12;      // batch
    const int lr = row0 & (NPOS - 1);
    unsigned wd[8];
#pragma unroll
    for (int i = 0; i < 8; ++i)
      wd[i] = (unsigned)f2bf(acc[2 * i]) | ((unsigned)f2bf(acc[2 * i + 1]) << 16);
    uint4* dst = reinterpret_cast<uint4*>(h_t + ((size_t)(b * CDIM + t)) * NPOS + lr);
    dst[0] = make_uint4(wd[0], wd[1], wd[2], wd[3]);
    dst[1] = make_uint4(wd[4], wd[5], wd[6], wd[7]);
  }
  // f,g projections: thread t owns column (t&63), rows rb..rb+3
  {
    const int col = t & 63;
    const int rb = (t >> 6) * 4;
    float af[4] = {0.f, 0.f, 0.f, 0.f};
    float ag[4] = {0.f, 0.f, 0.f, 0.f};
    for (int k = 0; k < CDIM; k += 4) {
      const float wf0 = Wf[(size_t)(k + 0) * FDIM + col];
      const float wf1 = Wf[(size_t)(k + 1) * FDIM + col];
      const float wf2 = Wf[(size_t)(k + 2) * FDIM + col];
      const float wf3 = Wf[(size_t)(k + 3) * FDIM + col];
      const float wg0 = Wg[(size_t)(k + 0) * FDIM + col];
      const float wg1 = Wg[(size_t)(k + 1) * FDIM + col];
      const float wg2 = Wg[(size_t)(k + 2) * FDIM + col];
      const float wg3 = Wg[(size_t)(k + 3) * FDIM + col];
#pragma unroll
      for (int r = 0; r < 4; ++r) {
        const float4 xv = *reinterpret_cast<const float4*>(&xs[rb + r][k]);
        float a = af[r], bb = ag[r];
        a = fmaf(xv.x, wf0, a); a = fmaf(xv.y, wf1, a);
        a = fmaf(xv.z, wf2, a); a = fmaf(xv.w, wf3, a);
        bb = fmaf(xv.x, wg0, bb); bb = fmaf(xv.y, wg1, bb);
        bb = fmaf(xv.z, wg2, bb); bb = fmaf(xv.w, wg3, bb);
        af[r] = a; ag[r] = bb;
      }
    }
#pragma unroll
    for (int r = 0; r < 4; ++r) {
      f[(size_t)(row0 + rb + r) * FDIM + col] = af[r];
      g[(size_t)(row0 + rb + r) * FDIM + col] = ag[r];
    }
  }
}

// ---------------------------------------------------------------------------
// Kernel 2: s = g @ f^T (fp32, exact). Writes RAW s into the beta region of
// d_out; tracks per-row online (max,sumexp) -> mrow/lrow.
// fs tile is XOR-swizzled: chunk kq of row r stored at kq ^ (r>>3) — kills
// the 16-way bank conflict (row stride 8*64 floats == 0 mod 32 banks).
// ---------------------------------------------------------------------------
__global__ __launch_bounds__(256) void qk_kernel(
    const float* __restrict__ f, const float* __restrict__ g,
    float* __restrict__ sraw, float* __restrict__ mrow, float* __restrict__ lrow) {
  __shared__ float gs[32][68];
  __shared__ float4 fsv[128][16];   // swizzled [row][chunk]
  const int b = blockIdx.y;
  const int row0 = blockIdx.x * 32;
  const int t = threadIdx.x;
  const int rg = t >> 4;   // 0..15 -> rows rg*2, rg*2+1
  const int cg = t & 15;   // 0..15 -> cols cg*8 .. cg*8+7 (within 128-chunk)

  {
    const float4* gv = reinterpret_cast<const float4*>(g + ((size_t)b * NPOS + row0) * FDIM);
#pragma unroll
    for (int q = 0; q < 2; ++q) {
      const int id = t + 256 * q;
      const float4 v = gv[id];
      const int r = id >> 4, kq = id & 15;
      *reinterpret_cast<float4*>(&gs[r][kq * 4]) = v;
    }
  }

  float m0 = -1e30f, m1 = -1e30f, l0 = 0.f, l1 = 0.f;
  float* srow0 = sraw + (size_t)b * NPOS * NPOS + (size_t)(row0 + rg * 2 + 0) * NPOS;
  float* srow1 = srow0 + NPOS;

  for (int ch = 0; ch < 32; ++ch) {
    __syncthreads();
    {
      const float4* fv = reinterpret_cast<const float4*>(f + ((size_t)b * NPOS + ch * 128) * FDIM);
#pragma unroll
      for (int q = 0; q < 8; ++q) {
        const int id = t + 256 * q;
        const float4 v = fv[id];
        const int r = id >> 4, kq = id & 15;
        fsv[r][kq ^ (r >> 3)] = v;
      }
    }
    __syncthreads();

    float acc0[8], acc1[8];
#pragma unroll
    for (int j = 0; j < 8; ++j) { acc0[j] = 0.f; acc1[j] = 0.f; }
#pragma unroll
    for (int k = 0; k < FDIM; k += 4) {
      const int kq = k >> 2;
      const float4 a0 = *reinterpret_cast<const float4*>(&gs[rg * 2 + 0][k]);
      const float4 a1 = *reinterpret_cast<const float4*>(&gs[rg * 2 + 1][k]);
#pragma unroll
      for (int j = 0; j < 8; ++j) {
        const float4 bq = fsv[cg * 8 + j][kq ^ cg];
        float s0 = acc0[j], s1 = acc1[j];
        s0 = fmaf(a0.x, bq.x, s0); s0 = fmaf(a0.y, bq.y, s0);
        s0 = fmaf(a0.z, bq.z, s0); s0 = fmaf(a0.w, bq.w, s0);
        s1 = fmaf(a1.x, bq.x, s1); s1 = fmaf(a1.y, bq.y, s1);
        s1 = fmaf(a1.z, bq.z, s1); s1 = fmaf(a1.w, bq.w, s1);
        acc0[j] = s0; acc1[j] = s1;
      }
    }

    const int cbase = ch * 128 + cg * 8;
    *reinterpret_cast<float4*>(&srow0[cbase]) = make_float4(acc0[0], acc0[1], acc0[2], acc0[3]);
    *reinterpret_cast<float4*>(&srow0[cbase + 4]) = make_float4(acc0[4], acc0[5], acc0[6], acc0[7]);
    *reinterpret_cast<float4*>(&srow1[cbase]) = make_float4(acc1[0], acc1[1], acc1[2], acc1[3]);
    *reinterpret_cast<float4*>(&srow1[cbase + 4]) = make_float4(acc1[4], acc1[5], acc1[6], acc1[7]);

    float cm0 = acc0[0], cm1 = acc1[0];
#pragma unroll
    for (int j = 1; j < 8; ++j) { cm0 = fmaxf(cm0, acc0[j]); cm1 = fmaxf(cm1, acc1[j]); }
    if (cm0 > m0) { l0 *= __expf(m0 - cm0); m0 = cm0; }
    if (cm1 > m1) { l1 *= __expf(m1 - cm1); m1 = cm1; }
    float s0 = 0.f, s1 = 0.f;
#pragma unroll
    for (int j = 0; j < 8; ++j) { s0 += __expf(acc0[j] - m0); s1 += __expf(acc1[j] - m1); }
    l0 += s0; l1 += s1;
  }

#pragma unroll
  for (int off = 1; off < 16; off <<= 1) {
    const float om0 = __shfl_xor(m0, off), ol0 = __shfl_xor(l0, off);
    const float om1 = __shfl_xor(m1, off), ol1 = __shfl_xor(l1, off);
    float nm = fmaxf(m0, om0);
    l0 = l0 * __expf(m0 - nm) + ol0 * __expf(om0 - nm); m0 = nm;
    nm = fmaxf(m1, om1);
    l1 = l1 * __expf(m1 - nm) + ol1 * __expf(om1 - nm); m1 = nm;
  }
  if (cg == 0) {
    const int r = b * NPOS + row0 + rg * 2;
    mrow[r] = m0; lrow[r] = l0;
    mrow[r + 1] = m1; lrow[r + 1] = l1;
  }
}

// ---------------------------------------------------------------------------
// Kernel 3 (MFMA): beta = exp(s-m)/l written fp32 to d_out; o = beta @ h via
// bf16 mfma_f32_16x16x32; out = gamma*o + x.
// Block: 32 beta-rows x 256 cols, 512 threads (8 waves of 16r x 64c).
// LDS tiles XOR-swizzled on 16B chunks (row stride 128B == 0 mod banks).
// ---------------------------------------------------------------------------
__global__ __launch_bounds__(512) void pv_mfma_kernel(
    const unsigned short* __restrict__ h_t, const float* __restrict__ x,
    const float* __restrict__ mrow, const float* __restrict__ lrow,
    const float* __restrict__ gamma, float* __restrict__ beta,
    float* __restrict__ out) {
  __shared__ uint4 Alds[32][8];    // beta tile, bf16 [32 rows][64 k], swizzled chunks
  __shared__ uint4 Blds[256][8];   // h^T tile, bf16 [256 cols][64 k], swizzled chunks
  const int b = blockIdx.y;
  const int row0 = blockIdx.x * 32;
  const int t = threadIdx.x;
  const int w = t >> 6;          // wave 0..7
  const int l = t & 63;
  const int wrow = (w & 1) * 16;
  const int wcol = (w >> 1) * 64;

  const float gam = gamma[0];
  float* betab = beta + (size_t)b * NPOS * NPOS;

  // A-staging assignment (threads 0..255): row ar, 8-float chunk q
  const int sar = t >> 3;        // 0..31 (valid for t<256)
  const int sq = t & 7;
  float mm = 0.f, il = 0.f;
  if (t < 256) {
    mm = mrow[b * NPOS + row0 + sar];
    il = __frcp_rn(lrow[b * NPOS + row0 + sar]);
  }
  // B-staging assignment: all 512 threads, 4 chunks each
  const int shr = t & 255;       // h_t row (= o column) 0..255
  const int shalf = t >> 8;      // chunks shalf*4 .. +3

  f32x4 acc[4];
#pragma unroll
  for (int c = 0; c < 4; ++c) acc[c] = (f32x4){0.f, 0.f, 0.f, 0.f};

  const int ar = wrow + (l & 15);
  const int fa = (ar >> 1) & 7;

  for (int kt = 0; kt < 64; ++kt) {
    const int k0 = kt * 64;
    __syncthreads();
    // ---- stage B: h_t[b][shr][k0 + 64) -> Blds
    {
      const unsigned short* src = h_t + ((size_t)(b * CDIM + shr)) * NPOS + k0;
#pragma unroll
      for (int j = 0; j < 4; ++j) {
        const int q = shalf * 4 + j;
        const uint4 v = *reinterpret_cast<const uint4*>(src + q * 8);
        Blds[shr][q ^ ((shr >> 1) & 7)] = v;
      }
    }
    // ---- stage A: read raw s, beta=exp(s-m)/l, write beta fp32, bf16 -> Alds
    if (t < 256) {
      float* srow = betab + (size_t)(row0 + sar) * NPOS + k0 + sq * 8;
      float4 v0 = *reinterpret_cast<const float4*>(srow);
      float4 v1 = *reinterpret_cast<const float4*>(srow + 4);
      v0.x = __expf(v0.x - mm) * il; v0.y = __expf(v0.y - mm) * il;
      v0.z = __expf(v0.z - mm) * il; v0.w = __expf(v0.w - mm) * il;
      v1.x = __expf(v1.x - mm) * il; v1.y = __expf(v1.y - mm) * il;
      v1.z = __expf(v1.z - mm) * il; v1.w = __expf(v1.w - mm) * il;
      *reinterpret_cast<float4*>(srow) = v0;
      *reinterpret_cast<float4*>(srow + 4) = v1;
      uint4 pk;
      pk.x = (unsigned)f2bf(v0.x) | ((unsigned)f2bf(v0.y) << 16);
      pk.y = (unsigned)f2bf(v0.z) | ((unsigned)f2bf(v0.w) << 16);
      pk.z = (unsigned)f2bf(v1.x) | ((unsigned)f2bf(v1.y) << 16);
      pk.w = (unsigned)f2bf(v1.z) | ((unsigned)f2bf(v1.w) << 16);
      Alds[sar][sq ^ ((sar >> 1) & 7)] = pk;
    }
    __syncthreads();
    // ---- MFMA: 2 k-steps of 32, 4 col-tiles per wave
#pragma unroll
    for (int ks = 0; ks < 2; ++ks) {
      const int qk = ks * 4 + (l >> 4);
      uint4 au = Alds[ar][qk ^ fa];
      short8 afr = *reinterpret_cast<short8*>(&au);
#pragma unroll
      for (int c = 0; c < 4; ++c) {
        const int br = wcol + 16 * c + (l & 15);
        uint4 bu = Blds[br][qk ^ ((br >> 1) & 7)];
        short8 bfr = *reinterpret_cast<short8*>(&bu);
        acc[c] = __builtin_amdgcn_mfma_f32_16x16x32_bf16(afr, bfr, acc[c], 0, 0, 0);
      }
    }
  }

  // epilogue: out = gamma*o + x ; C/D layout col=lane&15, row=(lane>>4)*4+reg
#pragma unroll
  for (int c = 0; c < 4; ++c) {
#pragma unroll
    for (int r = 0; r < 4; ++r) {
      const int orow = row0 + wrow + (l >> 4) * 4 + r;
      const int ocol = wcol + 16 * c + (l & 15);
      const size_t idx = ((size_t)b * NPOS + orow) * CDIM + ocol;
      out[idx] = fmaf(gam, acc[c][r], x[idx]);
    }
  }
}

extern "C" void kernel_launch(void* const* d_in, const int* in_sizes, int n_in,
                              void* d_out, int out_size, void* d_ws, size_t ws_size,
                              hipStream_t stream) {
  (void)in_sizes; (void)n_in; (void)out_size; (void)ws_size;
  const float* x = (const float*)d_in[0];
  const float* Wf = (const float*)d_in[1];
  const float* Wg = (const float*)d_in[2];
  const float* Wh = (const float*)d_in[3];
  const float* gamma = (const float*)d_in[4];

  float* out = (float*)d_out;                                  // [2*4096*256]
  float* beta = out + (size_t)2 * NPOS * CDIM;                 // [2*4096*4096]

  unsigned short* h_t = (unsigned short*)d_ws;                 // [2*256*4096] bf16
  float* f = (float*)((char*)d_ws + (size_t)2 * CDIM * NPOS * 2);  // [8192*64]
  float* g = f + (size_t)2 * NPOS * FDIM;                      // [8192*64]
  float* mrow = g + (size_t)2 * NPOS * FDIM;                   // [8192]
  float* lrow = mrow + 2 * NPOS;                               // [8192]

  hipLaunchKernelGGL(proj_kernel, dim3(2 * NPOS / 16), dim3(256), 0, stream,
                     x, Wf, Wg, Wh, f, g, h_t);
  hipLaunchKernelGGL(qk_kernel, dim3(NPOS / 32, 2), dim3(256), 0, stream,
                     f, g, beta, mrow, lrow);
  hipLaunchKernelGGL(pv_mfma_kernel, dim3(NPOS / 32, 2), dim3(512), 0, stream,
                     h_t, x, mrow, lrow, gamma, beta, out);
}